// Round 15
// baseline (276.490 us; speedup 1.0000x reference)
//
#include <hip/hip_runtime.h>

// Problem constants (match reference setup_inputs)
constexpr int NN = 50000;     // nodes
constexpr int NE = 1600000;   // edges
constexpr int H  = 128;       // feature dim (F_IN == H)
constexpr int LH = 256;       // lstm hidden
constexpr int OD = 32;        // output dim
constexpr int NG = 64;        // graphs

// Bucketed CSR build: bucket = dst >> 7 (128 nodes per bucket)
constexpr int NBKT  = (NN + 127) / 128;           // 391
constexpr int PARTE = 4096;                       // edges per k_part block
constexpr int NPARTB = (NE + PARTE - 1) / PARTE;  // 391
static_assert(NBKT <= 512, "k_bscan single block of 512 assumes NBKT <= 512");

// t'/agg layout: bf16 chunk-major, 4 chunks x 32 bf16 (64B line per chunk-row).
// Row NN is a zeroed dummy row (virtual edge padding target).
constexpr int BCH = 4;
constexpr int BCW = 32;
constexpr int NNP = NN + 1;   // rows per chunk incl. dummy

// LDS-staged edge window per gather block (ushorts). 64 nodes * avg 32 ~ 2048.
constexpr int LSZ = 4608;

typedef __attribute__((ext_vector_type(8))) short short8v;  // 8 bf16 (4 VGPR)
typedef __attribute__((ext_vector_type(4))) float f32x4;    // MFMA acc

union BF8 { uint4 u; short8v s; };

__device__ __forceinline__ unsigned short f2bf(float x) {
    unsigned int u = __float_as_uint(x);
    u = (u + 0x7FFFu + ((u >> 16) & 1u)) >> 16;   // round-to-nearest-even
    return (unsigned short)u;
}

// ---------------------------------------------------------------- dummy-row zeroer (row NN of each tb chunk)
__global__ __launch_bounds__(128) void k_zrow(unsigned short* __restrict__ tb) {
    int t = threadIdx.x;             // 128 threads: c = t>>5, f = t&31
    tb[((size_t)(t >> 5) * NNP + NN) * BCW + (t & 31)] = 0;
}

// ---------------------------------------------------------------- pass A: bucket histogram (LDS-aggregated)
__global__ __launch_bounds__(256) void k_bhist(const int* __restrict__ col,
                                               int* __restrict__ bktCnt) {
    __shared__ int h[NBKT];
    int t = threadIdx.x;
    for (int i = t; i < NBKT; i += 256) h[i] = 0;
    __syncthreads();
    for (int i = blockIdx.x * 256 + t; i < NE; i += gridDim.x * 256)
        atomicAdd(&h[col[i] >> 7], 1);
    __syncthreads();
    for (int i = t; i < NBKT; i += 256)
        if (h[i] > 0) atomicAdd(&bktCnt[i], h[i]);
}

// ---------------------------------------------------------------- pass B: scan bucket counts (single block, 512 thr)
__global__ __launch_bounds__(512) void k_bscan(const int* __restrict__ bktCnt,
                                               int* __restrict__ bktBase,
                                               int* __restrict__ bktCursor) {
    __shared__ int sh[512];
    int t = threadIdx.x;
    int v = (t < NBKT) ? bktCnt[t] : 0;
    sh[t] = v;
    __syncthreads();
    for (int off = 1; off < 512; off <<= 1) {
        int add = (t >= off) ? sh[t - off] : 0;
        __syncthreads();
        sh[t] += add;
        __syncthreads();
    }
    if (t < NBKT) {
        int excl = sh[t] - v;
        bktBase[t] = excl;
        bktCursor[t] = excl;
    }
    if (t == NBKT - 1) bktBase[NBKT] = sh[t];
}

// ---------------------------------------------------------------- pass C: partition edges, packed (src<<7 | dst&127)
__global__ __launch_bounds__(256) void k_part(const int* __restrict__ ei,
                                              int* __restrict__ bktCursor,
                                              int* __restrict__ part) {
    __shared__ int lcur[NBKT];
    __shared__ int lbase[NBKT];
    const int t = threadIdx.x;
    const int base = blockIdx.x * PARTE;
    int pk[16], bk[16];

    for (int i = t; i < NBKT; i += 256) lcur[i] = 0;
    __syncthreads();
#pragma unroll
    for (int j = 0; j < 16; ++j) {
        int e = base + j * 256 + t;
        if (e < NE) {
            int sr = ei[e];
            int ds = ei[NE + e];
            pk[j] = (sr << 7) | (ds & 127);
            bk[j] = ds >> 7;
            atomicAdd(&lcur[bk[j]], 1);
        }
    }
    __syncthreads();
    for (int i = t; i < NBKT; i += 256) {
        int c = lcur[i];
        lbase[i] = (c > 0) ? atomicAdd(&bktCursor[i], c) : 0;
        lcur[i] = 0;
    }
    __syncthreads();
#pragma unroll
    for (int j = 0; j < 16; ++j) {
        int e = base + j * 256 + t;
        if (e < NE) {
            int r = atomicAdd(&lcur[bk[j]], 1);
            part[lbase[bk[j]] + r] = pk[j];
        }
    }
}

// ---------------------------------------------------------------- pass D: per-bucket CSR finalize (all atomics in LDS)
__global__ __launch_bounds__(256) void k_bfill(const int* __restrict__ bktBase,
                                               const int* __restrict__ part,
                                               int* __restrict__ rp,
                                               int* __restrict__ cnt,
                                               float* __restrict__ dinv,
                                               unsigned short* __restrict__ srcs) {
    __shared__ int h[128];
    __shared__ int sc[128];
    __shared__ int cur[128];
    const int b = blockIdx.x, t = threadIdx.x;
    const int lo = bktBase[b], hi = bktBase[b + 1];

    if (t < 128) h[t] = 0;
    __syncthreads();
    for (int i = lo + t; i < hi; i += 256)
        atomicAdd(&h[part[i] & 127], 1);
    __syncthreads();
    int v = 0;
    if (t < 128) { v = h[t]; sc[t] = v; }
    __syncthreads();
    for (int off = 1; off < 128; off <<= 1) {
        int add = 0;
        if (t < 128 && t >= off) add = sc[t - off];
        __syncthreads();
        if (t < 128) sc[t] += add;
        __syncthreads();
    }
    if (t < 128) {
        int excl = sc[t] - v;
        cur[t] = lo + excl;
        int node = b * 128 + t;
        if (node < NN) {
            rp[node] = lo + excl;
            cnt[node] = v;
            dinv[node] = rsqrtf((float)v + 1.0f);   // self-loop adds 1
        }
    }
    __syncthreads();
    for (int i = lo + t; i < hi; i += 256) {
        int e = part[i];
        int pos = atomicAdd(&cur[e & 127], 1);
        srcs[pos] = (unsigned short)(e >> 7);
    }
}

// ---------------------------------------------------------------- GEMM t' = (relu?)(h) @ W * dinv[row], MFMA bf16
// Input: fp32 row-major (layer 0) or bf16 chunk-major [4][NNP][32] (layers 1,2).
// Output: bf16 chunk-major tb (rows < NN; dummy row NN untouched).
template <bool RELU, bool CHIN>
__global__ __launch_bounds__(256) void k_gemm(const float* __restrict__ hf,
                                              const unsigned short* __restrict__ hb,
                                              const float* __restrict__ W,
                                              const float* __restrict__ dinv,
                                              unsigned short* __restrict__ tb) {
    __shared__ uint4 lw[2048];   // [ct][ks][lane] -> 8 bf16 of B-fragment
    const int tid = threadIdx.x;

    // stage W (fp32 [128][128]) -> LDS bf16 fragments, once per block
    for (int e = tid; e < 2048; e += 256) {
        const int ct = e >> 8, ks = (e >> 6) & 3, l = e & 63;
        const int col = ct * 16 + (l & 15);
        const int kb  = ks * 32 + ((l >> 4) << 3);
        const float* wp = W + (size_t)kb * H + col;
        unsigned int p0 = (unsigned)f2bf(wp[0])     | ((unsigned)f2bf(wp[H])     << 16);
        unsigned int p1 = (unsigned)f2bf(wp[2 * H]) | ((unsigned)f2bf(wp[3 * H]) << 16);
        unsigned int p2 = (unsigned)f2bf(wp[4 * H]) | ((unsigned)f2bf(wp[5 * H]) << 16);
        unsigned int p3 = (unsigned)f2bf(wp[6 * H]) | ((unsigned)f2bf(wp[7 * H]) << 16);
        lw[e] = make_uint4(p0, p1, p2, p3);
    }
    __syncthreads();

    const int wave = tid >> 6, lane = tid & 63;
    const int rowbase = blockIdx.x * 64 + wave * 16;
    const int arow  = rowbase + (lane & 15);
    const int arowc = arow < NN ? arow : NN - 1;   // clamp loads
    const int koff  = (lane >> 4) << 3;

    f32x4 acc[8];
#pragma unroll
    for (int ct = 0; ct < 8; ++ct) acc[ct] = (f32x4){0.f, 0.f, 0.f, 0.f};

#pragma unroll
    for (int ks = 0; ks < 4; ++ks) {
        BF8 a;
        if (CHIN) {
            // bf16 chunk-major: feats ks*32+koff..+7 = one uint4
            a.u = *reinterpret_cast<const uint4*>(
                hb + ((size_t)ks * NNP + arowc) * BCW + koff);
            if (RELU) {
                unsigned int m;
                m = ((a.u.x >> 15) & 0x00010001u) * 0xFFFFu; a.u.x &= ~m;
                m = ((a.u.y >> 15) & 0x00010001u) * 0xFFFFu; a.u.y &= ~m;
                m = ((a.u.z >> 15) & 0x00010001u) * 0xFFFFu; a.u.z &= ~m;
                m = ((a.u.w >> 15) & 0x00010001u) * 0xFFFFu; a.u.w &= ~m;
            }
        } else {
            const int kb = ks * 32 + koff;
            const float* base = hf + (size_t)arowc * H + kb;
            float4 h0 = *reinterpret_cast<const float4*>(base);
            float4 h1 = *reinterpret_cast<const float4*>(base + 4);
            if (RELU) {
                h0.x = fmaxf(h0.x, 0.f); h0.y = fmaxf(h0.y, 0.f);
                h0.z = fmaxf(h0.z, 0.f); h0.w = fmaxf(h0.w, 0.f);
                h1.x = fmaxf(h1.x, 0.f); h1.y = fmaxf(h1.y, 0.f);
                h1.z = fmaxf(h1.z, 0.f); h1.w = fmaxf(h1.w, 0.f);
            }
            a.u = make_uint4(
                (unsigned)f2bf(h0.x) | ((unsigned)f2bf(h0.y) << 16),
                (unsigned)f2bf(h0.z) | ((unsigned)f2bf(h0.w) << 16),
                (unsigned)f2bf(h1.x) | ((unsigned)f2bf(h1.y) << 16),
                (unsigned)f2bf(h1.z) | ((unsigned)f2bf(h1.w) << 16));
        }
#pragma unroll
        for (int ct = 0; ct < 8; ++ct) {
            BF8 b;
            b.u = lw[(ct * 4 + ks) * 64 + lane];
            acc[ct] = __builtin_amdgcn_mfma_f32_16x16x32_bf16(a.s, b.s, acc[ct], 0, 0, 0);
        }
    }

    // epilogue: D lane mapping col=lane&15, row=(lane>>4)*4+r
    const int colb = lane & 15;
    const int rrow = rowbase + ((lane >> 4) << 2);
#pragma unroll
    for (int r = 0; r < 4; ++r) {
        const int row = rrow + r;
        if (row < NN) {
            const float d = dinv[row];
#pragma unroll
            for (int ct = 0; ct < 8; ++ct) {
                const int feat = ct * 16 + colb;
                tb[((size_t)(feat >> 5) * NNP + row) * BCW + (feat & 31)] =
                    f2bf(acc[ct][r] * d);
            }
        }
    }
}

// ---------------------------------------------------------------- gather (bf16 rows, LDS-staged u16 indices)
// o = bg + dinv[n] * (t'[n] + sum_e t'[src[e]]) ; t' bf16, accum fp32.
// Virtual padding: edge list processed in full 8-tiles; out-of-range slots
// select the zeroed dummy row NN (L1-resident) -> no serial tail.
// POOL=0: write o as bf16 to aggb. POOL=1: fused mean-pool (shuffle-tree).
template <int POOL>
__global__ __launch_bounds__(256) void k_gather(const int* __restrict__ rp,
                                                const int* __restrict__ cnt,
                                                const unsigned short* __restrict__ srcs,
                                                const float* __restrict__ dinv,
                                                const float* __restrict__ bg,
                                                const unsigned short* __restrict__ tb,
                                                unsigned short* __restrict__ aggb,
                                                const int* __restrict__ batch,
                                                float* __restrict__ pooled) {
    __shared__ unsigned short lsrcs[LSZ + 8];
    const int tid  = threadIdx.x;
    const int wv   = tid >> 6;         // 0..3
    const int lane = tid & 63;
    const int slot = lane >> 2;        // node group 0..15
    const int l4   = lane & 3;         // uint4 index within 64B row
    const int c    = blockIdx.x & 3;   // bf16 chunk (XCD affinity)
    const int nb   = blockIdx.x >> 2;  // node block (64 nodes)
    const int n0   = nb * 64;
    const int n    = n0 + wv * 16 + slot;

    const int eLo = rp[n0];
    int nLast = n0 + 63; if (nLast >= NN) nLast = NN - 1;
    const int eHi = rp[nLast] + cnt[nLast];
    const bool staged = (eHi - eLo) <= LSZ;   // block-uniform

    if (staged) {
        for (int i = eLo + tid; i < eHi; i += 256)
            lsrcs[i - eLo] = srcs[i];
    }

    __shared__ float psum[4][32];   // POOL accumulator (unused if POOL==0)
    int g0 = 0, gspan = 0;
    if (POOL) {
        if (tid < 128) psum[tid >> 5][tid & 31] = 0.f;
        g0 = batch[n0];
        gspan = batch[nLast] - g0;   // block-uniform
    }
    __syncthreads();

    if (n >= NN) return;

    const uint4* __restrict__ tb4 =
        reinterpret_cast<const uint4*>(tb) + (size_t)c * NNP * 4;
    const float4 bg0 = *reinterpret_cast<const float4*>(bg + c * BCW + l4 * 8);
    const float4 bg1 = *reinterpret_cast<const float4*>(bg + c * BCW + l4 * 8 + 4);

    const int i0   = rp[n];
    const int deg  = cnt[n];
    const int end  = i0 + deg;
    const int endP = i0 + ((deg + 7) & ~7);
    float4 p = make_float4(0.f, 0.f, 0.f, 0.f);
    float4 q = make_float4(0.f, 0.f, 0.f, 0.f);

#define ACC8(v)                                                        \
    do {                                                               \
        p.x += __uint_as_float((v).x << 16);                           \
        p.y += __uint_as_float((v).x & 0xFFFF0000u);                   \
        p.z += __uint_as_float((v).y << 16);                           \
        p.w += __uint_as_float((v).y & 0xFFFF0000u);                   \
        q.x += __uint_as_float((v).z << 16);                           \
        q.y += __uint_as_float((v).z & 0xFFFF0000u);                   \
        q.z += __uint_as_float((v).w << 16);                           \
        q.w += __uint_as_float((v).w & 0xFFFF0000u);                   \
    } while (0)

    if (staged) {
        for (int i = i0; i < endP; i += 8) {
            const int j = i - eLo;
            int s0 = (i + 0 < end) ? (int)lsrcs[j + 0] : NN;
            int s1 = (i + 1 < end) ? (int)lsrcs[j + 1] : NN;
            int s2 = (i + 2 < end) ? (int)lsrcs[j + 2] : NN;
            int s3 = (i + 3 < end) ? (int)lsrcs[j + 3] : NN;
            int s4 = (i + 4 < end) ? (int)lsrcs[j + 4] : NN;
            int s5 = (i + 5 < end) ? (int)lsrcs[j + 5] : NN;
            int s6 = (i + 6 < end) ? (int)lsrcs[j + 6] : NN;
            int s7 = (i + 7 < end) ? (int)lsrcs[j + 7] : NN;
            uint4 v0 = tb4[(size_t)s0 * 4 + l4];
            uint4 v1 = tb4[(size_t)s1 * 4 + l4];
            uint4 v2 = tb4[(size_t)s2 * 4 + l4];
            uint4 v3 = tb4[(size_t)s3 * 4 + l4];
            uint4 v4 = tb4[(size_t)s4 * 4 + l4];
            uint4 v5 = tb4[(size_t)s5 * 4 + l4];
            uint4 v6 = tb4[(size_t)s6 * 4 + l4];
            uint4 v7 = tb4[(size_t)s7 * 4 + l4];
            ACC8(v0); ACC8(v1); ACC8(v2); ACC8(v3);
            ACC8(v4); ACC8(v5); ACC8(v6); ACC8(v7);
        }
    } else {
        for (int i = i0; i < endP; i += 8) {
            int s0 = (i + 0 < end) ? (int)srcs[i + 0] : NN;
            int s1 = (i + 1 < end) ? (int)srcs[i + 1] : NN;
            int s2 = (i + 2 < end) ? (int)srcs[i + 2] : NN;
            int s3 = (i + 3 < end) ? (int)srcs[i + 3] : NN;
            int s4 = (i + 4 < end) ? (int)srcs[i + 4] : NN;
            int s5 = (i + 5 < end) ? (int)srcs[i + 5] : NN;
            int s6 = (i + 6 < end) ? (int)srcs[i + 6] : NN;
            int s7 = (i + 7 < end) ? (int)srcs[i + 7] : NN;
            uint4 v0 = tb4[(size_t)s0 * 4 + l4];
            uint4 v1 = tb4[(size_t)s1 * 4 + l4];
            uint4 v2 = tb4[(size_t)s2 * 4 + l4];
            uint4 v3 = tb4[(size_t)s3 * 4 + l4];
            uint4 v4 = tb4[(size_t)s4 * 4 + l4];
            uint4 v5 = tb4[(size_t)s5 * 4 + l4];
            uint4 v6 = tb4[(size_t)s6 * 4 + l4];
            uint4 v7 = tb4[(size_t)s7 * 4 + l4];
            ACC8(v0); ACC8(v1); ACC8(v2); ACC8(v3);
            ACC8(v4); ACC8(v5); ACC8(v6); ACC8(v7);
        }
    }

    uint4 sv = tb4[(size_t)n * 4 + l4];   // self-loop term
    ACC8(sv);
#undef ACC8

    const float d = dinv[n];
    float4 o0, o1;
    o0.x = fmaf(p.x, d, bg0.x); o0.y = fmaf(p.y, d, bg0.y);
    o0.z = fmaf(p.z, d, bg0.z); o0.w = fmaf(p.w, d, bg0.w);
    o1.x = fmaf(q.x, d, bg1.x); o1.y = fmaf(q.y, d, bg1.y);
    o1.z = fmaf(q.z, d, bg1.z); o1.w = fmaf(q.w, d, bg1.w);

    if (POOL == 0) {
        uint4 u;
        u.x = (unsigned)f2bf(o0.x) | ((unsigned)f2bf(o0.y) << 16);
        u.y = (unsigned)f2bf(o0.z) | ((unsigned)f2bf(o0.w) << 16);
        u.z = (unsigned)f2bf(o1.x) | ((unsigned)f2bf(o1.y) << 16);
        u.w = (unsigned)f2bf(o1.z) | ((unsigned)f2bf(o1.w) << 16);
        *reinterpret_cast<uint4*>(aggb + ((size_t)c * NNP + n) * BCW + l4 * 8) = u;
    } else {
        // relu + mean-pool
        o0.x = fmaxf(o0.x, 0.f); o0.y = fmaxf(o0.y, 0.f);
        o0.z = fmaxf(o0.z, 0.f); o0.w = fmaxf(o0.w, 0.f);
        o1.x = fmaxf(o1.x, 0.f); o1.y = fmaxf(o1.y, 0.f);
        o1.z = fmaxf(o1.z, 0.f); o1.w = fmaxf(o1.w, 0.f);
        if (gspan > 3) {
            float* dst = pooled + (size_t)batch[n] * H + c * BCW + l4 * 8;
            atomicAdd(dst + 0, o0.x); atomicAdd(dst + 1, o0.y);
            atomicAdd(dst + 2, o0.z); atomicAdd(dst + 3, o0.w);
            atomicAdd(dst + 4, o1.x); atomicAdd(dst + 5, o1.y);
            atomicAdd(dst + 6, o1.z); atomicAdd(dst + 7, o1.w);
        } else if (gspan == 0) {
            // single-graph block (common): shuffle-tree over slot bits (2..5)
#pragma unroll
            for (int m = 4; m <= 32; m <<= 1) {
                o0.x += __shfl_xor(o0.x, m); o0.y += __shfl_xor(o0.y, m);
                o0.z += __shfl_xor(o0.z, m); o0.w += __shfl_xor(o0.w, m);
                o1.x += __shfl_xor(o1.x, m); o1.y += __shfl_xor(o1.y, m);
                o1.z += __shfl_xor(o1.z, m); o1.w += __shfl_xor(o1.w, m);
            }
            if (slot == 0) {      // lane = l4 (0..3): wave-sum for feats l4*8..+7
                float* ps = &psum[wv][l4 * 8];
                ps[0] = o0.x; ps[1] = o0.y; ps[2] = o0.z; ps[3] = o0.w;
                ps[4] = o1.x; ps[5] = o1.y; ps[6] = o1.z; ps[7] = o1.w;
            }
            __syncthreads();
            if (tid < 32) {
                float v = psum[0][tid] + psum[1][tid] + psum[2][tid] + psum[3][tid];
                atomicAdd(&pooled[(size_t)g0 * H + c * BCW + tid], v);
            }
        } else {
            // graph-boundary block (~8%): LDS atomics (contention amortized)
            const int gi = batch[n] - g0;
            float* ps = &psum[gi][l4 * 8];
            atomicAdd(ps + 0, o0.x); atomicAdd(ps + 1, o0.y);
            atomicAdd(ps + 2, o0.z); atomicAdd(ps + 3, o0.w);
            atomicAdd(ps + 4, o1.x); atomicAdd(ps + 5, o1.y);
            atomicAdd(ps + 6, o1.z); atomicAdd(ps + 7, o1.w);
            __syncthreads();
            if (tid < 128) {
                int gi2 = tid >> 5, f = tid & 31;
                float v = psum[gi2][f];
                if (v != 0.f)
                    atomicAdd(&pooled[(size_t)(g0 + gi2) * H + c * BCW + f], v);
            }
        }
    }
}

// ---------------------------------------------------------------- helpers
__device__ __forceinline__ int lower_bound_dev(const int* __restrict__ b, int v) {
    int lo = 0, hi = NN;
    while (lo < hi) {
        int m = (lo + hi) >> 1;
        if (b[m] < v) lo = m + 1; else hi = m;
    }
    return lo;
}

// ---------------------------------------------------------------- LSTM (single step, h0=c0=0) + output head, fused
__global__ __launch_bounds__(256) void k_lstm(const float* __restrict__ pooled,
                                              const int* __restrict__ batch,
                                              const float* __restrict__ W_ih,
                                              const float* __restrict__ b_ih,
                                              const float* __restrict__ b_hh,
                                              const float* __restrict__ W_out,
                                              const float* __restrict__ b_out,
                                              float* __restrict__ out) {
    __shared__ __align__(16) float p[H];
    __shared__ __align__(16) float hn[LH];
    int g = blockIdx.x, t = threadIdx.x;
    if (t < H) {
        int s = lower_bound_dev(batch, g);
        int e = lower_bound_dev(batch, g + 1);
        p[t] = pooled[g * H + t] / fmaxf((float)(e - s), 1.f);
    }
    __syncthreads();

    // gate rows (torch order i,f,g,o): f unused (c0=0)
    float si = b_ih[t] + b_hh[t];
    float sg = b_ih[2 * LH + t] + b_hh[2 * LH + t];
    float so = b_ih[3 * LH + t] + b_hh[3 * LH + t];
    const float* wi = W_ih + (size_t)t * H;
    const float* wg = W_ih + (size_t)(2 * LH + t) * H;
    const float* wo = W_ih + (size_t)(3 * LH + t) * H;
    for (int k = 0; k < H; k += 4) {
        float4 pv = *reinterpret_cast<const float4*>(&p[k]);
        float4 a = *reinterpret_cast<const float4*>(wi + k);
        si += pv.x * a.x + pv.y * a.y + pv.z * a.z + pv.w * a.w;
        float4 b = *reinterpret_cast<const float4*>(wg + k);
        sg += pv.x * b.x + pv.y * b.y + pv.z * b.z + pv.w * b.w;
        float4 c = *reinterpret_cast<const float4*>(wo + k);
        so += pv.x * c.x + pv.y * c.y + pv.z * c.z + pv.w * c.w;
    }
    float ig = 1.f / (1.f + expf(-si));
    float cc = ig * tanhf(sg);
    float og = 1.f / (1.f + expf(-so));
    hn[t] = og * tanhf(cc);
    __syncthreads();

    if (t < OD) {
        float acc = b_out[t];
        const float* wr = W_out + (size_t)t * LH;
        for (int k = 0; k < LH; k += 4) {
            float4 hv = *reinterpret_cast<const float4*>(&hn[k]);
            float4 wv = *reinterpret_cast<const float4*>(wr + k);
            acc += hv.x * wv.x + hv.y * wv.y + hv.z * wv.z + hv.w * wv.w;
        }
        out[g * OD + t] = acc;
    }
}

// ----------------------------------------------------------------
extern "C" void kernel_launch(void* const* d_in, const int* in_sizes, int n_in,
                              void* d_out, int out_size, void* d_ws, size_t ws_size,
                              hipStream_t stream) {
    const float* x     = (const float*)d_in[0];
    const int*   ei    = (const int*)d_in[1];   // [2][NE]: rows then cols
    const int*   batch = (const int*)d_in[2];
    const float* Wg    = (const float*)d_in[3]; // [3][128][128]
    const float* bg    = (const float*)d_in[4]; // [3][128]
    const float* W_ih  = (const float*)d_in[5]; // [1024][128]
    const float* b_ih  = (const float*)d_in[7];
    const float* b_hh  = (const float*)d_in[8];
    const float* W_out = (const float*)d_in[9]; // [32][256]
    const float* b_out = (const float*)d_in[10];
    float* out = (float*)d_out;

    // workspace layout (~36 MB)
    unsigned short* tb   = (unsigned short*)d_ws;       // [4][NNP][32] bf16
    unsigned short* aggb = tb + (size_t)4 * NNP * BCW;  // [4][NNP][32] bf16
    int*   part      = (int*)(aggb + (size_t)4 * NNP * BCW); // NE ints (packed)
    float* dinv      = (float*)(part + NE);             // NN
    float* pooled    = dinv + NN;                       // NG*H
    int*   cnt       = (int*)(pooled + NG * H);         // NN
    int*   rp        = cnt + NN;                        // NN
    unsigned short* srcs = (unsigned short*)(rp + NN);  // NE+16 u16
    int*   bktCnt    = (int*)(srcs + NE + 16);          // NBKT
    int*   bktBase   = bktCnt + NBKT;                   // NBKT+1
    int*   bktCursor = bktBase + NBKT + 1;              // NBKT

    hipMemsetAsync(bktCnt, 0, NBKT * sizeof(int), stream);
    hipMemsetAsync(pooled, 0, NG * H * sizeof(float), stream);
    k_zrow<<<1, 128, 0, stream>>>(tb);

    // CSR build (by destination) — bucketed counting sort (128-node buckets)
    k_bhist<<<1024, 256, 0, stream>>>(ei + NE, bktCnt);
    k_bscan<<<1, 512, 0, stream>>>(bktCnt, bktBase, bktCursor);
    k_part <<<NPARTB, 256, 0, stream>>>(ei, bktCursor, part);
    k_bfill<<<NBKT, 256, 0, stream>>>(bktBase, part, rp, cnt, dinv, srcs);

    const int gemmBlocks = (NN + 63) / 64;
    const int gathBlocks = ((NN + 63) / 64) * BCH;   // 782 * 4 = 3128

    // layer 0: x (fp32 row-major) -> tb -> aggb
    k_gemm<false, false><<<gemmBlocks, 256, 0, stream>>>(x, nullptr, Wg, dinv, tb);
    k_gather<0><<<gathBlocks, 256, 0, stream>>>(rp, cnt, srcs, dinv, bg, tb, aggb, batch, pooled);
    // layer 1: relu(aggb) -> tb -> aggb
    k_gemm<true, true><<<gemmBlocks, 256, 0, stream>>>(nullptr, aggb, Wg + H * H, dinv, tb);
    k_gather<0><<<gathBlocks, 256, 0, stream>>>(rp, cnt, srcs, dinv, bg + H, tb, aggb, batch, pooled);
    // layer 2: relu(aggb) -> tb -> pooled (pool fused)
    k_gemm<true, true><<<gemmBlocks, 256, 0, stream>>>(nullptr, aggb, Wg + 2 * H * H, dinv, tb);
    k_gather<1><<<gathBlocks, 256, 0, stream>>>(rp, cnt, srcs, dinv, bg + 2 * H, tb, nullptr, batch, pooled);

    k_lstm<<<NG, 256, 0, stream>>>(pooled, batch, W_ih, b_ih, b_hh, W_out, b_out, out);
}

// Round 16
// 266.503 us; speedup vs baseline: 1.0375x; 1.0375x over previous
//
#include <hip/hip_runtime.h>

// Problem constants (match reference setup_inputs)
constexpr int NN = 50000;     // nodes
constexpr int NE = 1600000;   // edges
constexpr int H  = 128;       // feature dim (F_IN == H)
constexpr int LH = 256;       // lstm hidden
constexpr int OD = 32;        // output dim
constexpr int NG = 64;        // graphs

// Bucketed CSR build: bucket = dst >> 8 (256 nodes per bucket)
constexpr int NBKT  = (NN + 255) / 256;           // 196
constexpr int PARTE = 4096;                       // edges per k_part block
constexpr int NPARTB = (NE + PARTE - 1) / PARTE;  // 391
static_assert(NBKT <= 256, "single-block scan assumes NBKT <= 256");

// t'/agg layout: bf16 chunk-major, 4 chunks x 32 bf16 (64B line per chunk-row).
// Row NN is a zeroed dummy row (virtual edge padding target).
constexpr int BCH = 4;
constexpr int BCW = 32;
constexpr int NNP = NN + 1;   // rows per chunk incl. dummy

// LDS-staged edge window per gather block (ushorts). 64 nodes * avg 32 ~ 2048.
constexpr int LSZ = 4608;

typedef __attribute__((ext_vector_type(8))) short short8v;  // 8 bf16 (4 VGPR)
typedef __attribute__((ext_vector_type(4))) float f32x4;    // MFMA acc

union BF8 { uint4 u; short8v s; };

__device__ __forceinline__ unsigned short f2bf(float x) {
    unsigned int u = __float_as_uint(x);
    u = (u + 0x7FFFu + ((u >> 16) & 1u)) >> 16;   // round-to-nearest-even
    return (unsigned short)u;
}

// ---------------------------------------------------------------- pass A: bucket histogram (LDS-aggregated)
__global__ __launch_bounds__(256) void k_bhist(const int* __restrict__ col,
                                               int* __restrict__ bktCnt) {
    __shared__ int h[NBKT];
    int t = threadIdx.x;
    if (t < NBKT) h[t] = 0;
    __syncthreads();
    for (int i = blockIdx.x * 256 + t; i < NE; i += gridDim.x * 256)
        atomicAdd(&h[col[i] >> 8], 1);
    __syncthreads();
    if (t < NBKT && h[t] > 0) atomicAdd(&bktCnt[t], h[t]);
}

// ---------------------------------------------------------------- pass B: scan bucket counts + zero dummy rows
__global__ __launch_bounds__(256) void k_bscan(const int* __restrict__ bktCnt,
                                               int* __restrict__ bktBase,
                                               int* __restrict__ bktCursor,
                                               unsigned short* __restrict__ tb) {
    __shared__ int sh[256];
    int t = threadIdx.x;
    int v = (t < NBKT) ? bktCnt[t] : 0;
    sh[t] = v;
    __syncthreads();
    for (int off = 1; off < 256; off <<= 1) {
        int add = (t >= off) ? sh[t - off] : 0;
        __syncthreads();
        sh[t] += add;
        __syncthreads();
    }
    if (t < NBKT) {
        int excl = sh[t] - v;
        bktBase[t] = excl;
        bktCursor[t] = excl;
    }
    if (t == NBKT - 1) bktBase[NBKT] = sh[t];
    // zero the dummy row NN of each tb chunk (padding target)
    if (t < 128)
        tb[((size_t)(t >> 5) * NNP + NN) * BCW + (t & 31)] = 0;
}

// ---------------------------------------------------------------- pass C: partition edges, packed (src<<8 | dst&255)
__global__ __launch_bounds__(256) void k_part(const int* __restrict__ ei,
                                              int* __restrict__ bktCursor,
                                              int* __restrict__ part) {
    __shared__ int lcur[NBKT];
    __shared__ int lbase[NBKT];
    const int t = threadIdx.x;
    const int base = blockIdx.x * PARTE;
    int pk[16], bk[16];

    if (t < NBKT) lcur[t] = 0;
    __syncthreads();
#pragma unroll
    for (int j = 0; j < 16; ++j) {
        int e = base + j * 256 + t;
        if (e < NE) {
            int sr = ei[e];
            int ds = ei[NE + e];
            pk[j] = (sr << 8) | (ds & 255);
            bk[j] = ds >> 8;
            atomicAdd(&lcur[bk[j]], 1);
        }
    }
    __syncthreads();
    if (t < NBKT) {
        int c = lcur[t];
        lbase[t] = (c > 0) ? atomicAdd(&bktCursor[t], c) : 0;
        lcur[t] = 0;
    }
    __syncthreads();
#pragma unroll
    for (int j = 0; j < 16; ++j) {
        int e = base + j * 256 + t;
        if (e < NE) {
            int r = atomicAdd(&lcur[bk[j]], 1);
            part[lbase[bk[j]] + r] = pk[j];
        }
    }
}

// ---------------------------------------------------------------- pass D: per-bucket CSR finalize (all atomics in LDS)
__global__ __launch_bounds__(256) void k_bfill(const int* __restrict__ bktBase,
                                               const int* __restrict__ part,
                                               int* __restrict__ rp,
                                               int* __restrict__ cnt,
                                               float* __restrict__ dinv,
                                               unsigned short* __restrict__ srcs) {
    __shared__ int h[256];
    __shared__ int sc[256];
    __shared__ int cur[256];
    const int b = blockIdx.x, t = threadIdx.x;
    const int lo = bktBase[b], hi = bktBase[b + 1];

    h[t] = 0;
    __syncthreads();
    for (int i = lo + t; i < hi; i += 256)
        atomicAdd(&h[part[i] & 255], 1);
    __syncthreads();
    int v = h[t];
    sc[t] = v;
    __syncthreads();
    for (int off = 1; off < 256; off <<= 1) {
        int add = (t >= off) ? sc[t - off] : 0;
        __syncthreads();
        sc[t] += add;
        __syncthreads();
    }
    int excl = sc[t] - v;
    cur[t] = lo + excl;
    int node = b * 256 + t;
    if (node < NN) {
        rp[node] = lo + excl;
        cnt[node] = v;
        dinv[node] = rsqrtf((float)v + 1.0f);   // self-loop adds 1
    }
    __syncthreads();
    for (int i = lo + t; i < hi; i += 256) {
        int e = part[i];
        int pos = atomicAdd(&cur[e & 255], 1);
        srcs[pos] = (unsigned short)(e >> 8);
    }
}

// ---------------------------------------------------------------- GEMM t' = (relu?)(h) @ W * dinv[row], MFMA bf16
// Input: fp32 row-major (layer 0) or bf16 chunk-major [4][NNP][32] (layers 1,2).
// Output: bf16 chunk-major tb (rows < NN; dummy row NN untouched).
template <bool RELU, bool CHIN>
__global__ __launch_bounds__(256) void k_gemm(const float* __restrict__ hf,
                                              const unsigned short* __restrict__ hb,
                                              const float* __restrict__ W,
                                              const float* __restrict__ dinv,
                                              unsigned short* __restrict__ tb) {
    __shared__ uint4 lw[2048];   // [ct][ks][lane] -> 8 bf16 of B-fragment
    const int tid = threadIdx.x;

    // stage W (fp32 [128][128]) -> LDS bf16 fragments, once per block
    for (int e = tid; e < 2048; e += 256) {
        const int ct = e >> 8, ks = (e >> 6) & 3, l = e & 63;
        const int col = ct * 16 + (l & 15);
        const int kb  = ks * 32 + ((l >> 4) << 3);
        const float* wp = W + (size_t)kb * H + col;
        unsigned int p0 = (unsigned)f2bf(wp[0])     | ((unsigned)f2bf(wp[H])     << 16);
        unsigned int p1 = (unsigned)f2bf(wp[2 * H]) | ((unsigned)f2bf(wp[3 * H]) << 16);
        unsigned int p2 = (unsigned)f2bf(wp[4 * H]) | ((unsigned)f2bf(wp[5 * H]) << 16);
        unsigned int p3 = (unsigned)f2bf(wp[6 * H]) | ((unsigned)f2bf(wp[7 * H]) << 16);
        lw[e] = make_uint4(p0, p1, p2, p3);
    }
    __syncthreads();

    const int wave = tid >> 6, lane = tid & 63;
    const int rowbase = blockIdx.x * 64 + wave * 16;
    const int arow  = rowbase + (lane & 15);
    const int arowc = arow < NN ? arow : NN - 1;   // clamp loads
    const int koff  = (lane >> 4) << 3;

    f32x4 acc[8];
#pragma unroll
    for (int ct = 0; ct < 8; ++ct) acc[ct] = (f32x4){0.f, 0.f, 0.f, 0.f};

#pragma unroll
    for (int ks = 0; ks < 4; ++ks) {
        BF8 a;
        if (CHIN) {
            // bf16 chunk-major: feats ks*32+koff..+7 = one uint4
            a.u = *reinterpret_cast<const uint4*>(
                hb + ((size_t)ks * NNP + arowc) * BCW + koff);
            if (RELU) {
                unsigned int m;
                m = ((a.u.x >> 15) & 0x00010001u) * 0xFFFFu; a.u.x &= ~m;
                m = ((a.u.y >> 15) & 0x00010001u) * 0xFFFFu; a.u.y &= ~m;
                m = ((a.u.z >> 15) & 0x00010001u) * 0xFFFFu; a.u.z &= ~m;
                m = ((a.u.w >> 15) & 0x00010001u) * 0xFFFFu; a.u.w &= ~m;
            }
        } else {
            const int kb = ks * 32 + koff;
            const float* base = hf + (size_t)arowc * H + kb;
            float4 h0 = *reinterpret_cast<const float4*>(base);
            float4 h1 = *reinterpret_cast<const float4*>(base + 4);
            if (RELU) {
                h0.x = fmaxf(h0.x, 0.f); h0.y = fmaxf(h0.y, 0.f);
                h0.z = fmaxf(h0.z, 0.f); h0.w = fmaxf(h0.w, 0.f);
                h1.x = fmaxf(h1.x, 0.f); h1.y = fmaxf(h1.y, 0.f);
                h1.z = fmaxf(h1.z, 0.f); h1.w = fmaxf(h1.w, 0.f);
            }
            a.u = make_uint4(
                (unsigned)f2bf(h0.x) | ((unsigned)f2bf(h0.y) << 16),
                (unsigned)f2bf(h0.z) | ((unsigned)f2bf(h0.w) << 16),
                (unsigned)f2bf(h1.x) | ((unsigned)f2bf(h1.y) << 16),
                (unsigned)f2bf(h1.z) | ((unsigned)f2bf(h1.w) << 16));
        }
#pragma unroll
        for (int ct = 0; ct < 8; ++ct) {
            BF8 b;
            b.u = lw[(ct * 4 + ks) * 64 + lane];
            acc[ct] = __builtin_amdgcn_mfma_f32_16x16x32_bf16(a.s, b.s, acc[ct], 0, 0, 0);
        }
    }

    // epilogue: D lane mapping col=lane&15, row=(lane>>4)*4+r
    const int colb = lane & 15;
    const int rrow = rowbase + ((lane >> 4) << 2);
#pragma unroll
    for (int r = 0; r < 4; ++r) {
        const int row = rrow + r;
        if (row < NN) {
            const float d = dinv[row];
#pragma unroll
            for (int ct = 0; ct < 8; ++ct) {
                const int feat = ct * 16 + colb;
                tb[((size_t)(feat >> 5) * NNP + row) * BCW + (feat & 31)] =
                    f2bf(acc[ct][r] * d);
            }
        }
    }
}

// ---------------------------------------------------------------- gather (bf16 rows, LDS-staged u16 indices)
// o = bg + dinv[n] * (t'[n] + sum_e t'[src[e]]) ; t' bf16, accum fp32.
// Virtual padding: edge list processed in full 8-tiles; out-of-range slots
// select the zeroed dummy row NN (L1-resident) -> no serial tail.
// POOL=0: write o as bf16 to aggb. POOL=1: fused mean-pool (shuffle-tree).
template <int POOL>
__global__ __launch_bounds__(256) void k_gather(const int* __restrict__ rp,
                                                const int* __restrict__ cnt,
                                                const unsigned short* __restrict__ srcs,
                                                const float* __restrict__ dinv,
                                                const float* __restrict__ bg,
                                                const unsigned short* __restrict__ tb,
                                                unsigned short* __restrict__ aggb,
                                                const int* __restrict__ batch,
                                                float* __restrict__ pooled) {
    __shared__ unsigned short lsrcs[LSZ + 8];
    const int tid  = threadIdx.x;
    const int wv   = tid >> 6;         // 0..3
    const int lane = tid & 63;
    const int slot = lane >> 2;        // node group 0..15
    const int l4   = lane & 3;         // uint4 index within 64B row
    const int c    = blockIdx.x & 3;   // bf16 chunk (XCD affinity)
    const int nb   = blockIdx.x >> 2;  // node block (64 nodes)
    const int n0   = nb * 64;
    const int n    = n0 + wv * 16 + slot;

    const int eLo = rp[n0];
    int nLast = n0 + 63; if (nLast >= NN) nLast = NN - 1;
    const int eHi = rp[nLast] + cnt[nLast];
    const bool staged = (eHi - eLo) <= LSZ;   // block-uniform

    if (staged) {
        for (int i = eLo + tid; i < eHi; i += 256)
            lsrcs[i - eLo] = srcs[i];
    }

    __shared__ float psum[4][32];   // POOL accumulator (unused if POOL==0)
    int g0 = 0, gspan = 0;
    if (POOL) {
        if (tid < 128) psum[tid >> 5][tid & 31] = 0.f;
        g0 = batch[n0];
        gspan = batch[nLast] - g0;   // block-uniform
    }
    __syncthreads();

    if (n >= NN) return;

    const uint4* __restrict__ tb4 =
        reinterpret_cast<const uint4*>(tb) + (size_t)c * NNP * 4;
    const float4 bg0 = *reinterpret_cast<const float4*>(bg + c * BCW + l4 * 8);
    const float4 bg1 = *reinterpret_cast<const float4*>(bg + c * BCW + l4 * 8 + 4);

    const int i0   = rp[n];
    const int deg  = cnt[n];
    const int end  = i0 + deg;
    const int endP = i0 + ((deg + 7) & ~7);
    float4 p = make_float4(0.f, 0.f, 0.f, 0.f);
    float4 q = make_float4(0.f, 0.f, 0.f, 0.f);

#define ACC8(v)                                                        \
    do {                                                               \
        p.x += __uint_as_float((v).x << 16);                           \
        p.y += __uint_as_float((v).x & 0xFFFF0000u);                   \
        p.z += __uint_as_float((v).y << 16);                           \
        p.w += __uint_as_float((v).y & 0xFFFF0000u);                   \
        q.x += __uint_as_float((v).z << 16);                           \
        q.y += __uint_as_float((v).z & 0xFFFF0000u);                   \
        q.z += __uint_as_float((v).w << 16);                           \
        q.w += __uint_as_float((v).w & 0xFFFF0000u);                   \
    } while (0)

    if (staged) {
        for (int i = i0; i < endP; i += 8) {
            const int j = i - eLo;
            int s0 = (i + 0 < end) ? (int)lsrcs[j + 0] : NN;
            int s1 = (i + 1 < end) ? (int)lsrcs[j + 1] : NN;
            int s2 = (i + 2 < end) ? (int)lsrcs[j + 2] : NN;
            int s3 = (i + 3 < end) ? (int)lsrcs[j + 3] : NN;
            int s4 = (i + 4 < end) ? (int)lsrcs[j + 4] : NN;
            int s5 = (i + 5 < end) ? (int)lsrcs[j + 5] : NN;
            int s6 = (i + 6 < end) ? (int)lsrcs[j + 6] : NN;
            int s7 = (i + 7 < end) ? (int)lsrcs[j + 7] : NN;
            uint4 v0 = tb4[(size_t)s0 * 4 + l4];
            uint4 v1 = tb4[(size_t)s1 * 4 + l4];
            uint4 v2 = tb4[(size_t)s2 * 4 + l4];
            uint4 v3 = tb4[(size_t)s3 * 4 + l4];
            uint4 v4 = tb4[(size_t)s4 * 4 + l4];
            uint4 v5 = tb4[(size_t)s5 * 4 + l4];
            uint4 v6 = tb4[(size_t)s6 * 4 + l4];
            uint4 v7 = tb4[(size_t)s7 * 4 + l4];
            ACC8(v0); ACC8(v1); ACC8(v2); ACC8(v3);
            ACC8(v4); ACC8(v5); ACC8(v6); ACC8(v7);
        }
    } else {
        for (int i = i0; i < endP; i += 8) {
            int s0 = (i + 0 < end) ? (int)srcs[i + 0] : NN;
            int s1 = (i + 1 < end) ? (int)srcs[i + 1] : NN;
            int s2 = (i + 2 < end) ? (int)srcs[i + 2] : NN;
            int s3 = (i + 3 < end) ? (int)srcs[i + 3] : NN;
            int s4 = (i + 4 < end) ? (int)srcs[i + 4] : NN;
            int s5 = (i + 5 < end) ? (int)srcs[i + 5] : NN;
            int s6 = (i + 6 < end) ? (int)srcs[i + 6] : NN;
            int s7 = (i + 7 < end) ? (int)srcs[i + 7] : NN;
            uint4 v0 = tb4[(size_t)s0 * 4 + l4];
            uint4 v1 = tb4[(size_t)s1 * 4 + l4];
            uint4 v2 = tb4[(size_t)s2 * 4 + l4];
            uint4 v3 = tb4[(size_t)s3 * 4 + l4];
            uint4 v4 = tb4[(size_t)s4 * 4 + l4];
            uint4 v5 = tb4[(size_t)s5 * 4 + l4];
            uint4 v6 = tb4[(size_t)s6 * 4 + l4];
            uint4 v7 = tb4[(size_t)s7 * 4 + l4];
            ACC8(v0); ACC8(v1); ACC8(v2); ACC8(v3);
            ACC8(v4); ACC8(v5); ACC8(v6); ACC8(v7);
        }
    }

    uint4 sv = tb4[(size_t)n * 4 + l4];   // self-loop term
    ACC8(sv);
#undef ACC8

    const float d = dinv[n];
    float4 o0, o1;
    o0.x = fmaf(p.x, d, bg0.x); o0.y = fmaf(p.y, d, bg0.y);
    o0.z = fmaf(p.z, d, bg0.z); o0.w = fmaf(p.w, d, bg0.w);
    o1.x = fmaf(q.x, d, bg1.x); o1.y = fmaf(q.y, d, bg1.y);
    o1.z = fmaf(q.z, d, bg1.z); o1.w = fmaf(q.w, d, bg1.w);

    if (POOL == 0) {
        uint4 u;
        u.x = (unsigned)f2bf(o0.x) | ((unsigned)f2bf(o0.y) << 16);
        u.y = (unsigned)f2bf(o0.z) | ((unsigned)f2bf(o0.w) << 16);
        u.z = (unsigned)f2bf(o1.x) | ((unsigned)f2bf(o1.y) << 16);
        u.w = (unsigned)f2bf(o1.z) | ((unsigned)f2bf(o1.w) << 16);
        *reinterpret_cast<uint4*>(aggb + ((size_t)c * NNP + n) * BCW + l4 * 8) = u;
    } else {
        // relu + mean-pool
        o0.x = fmaxf(o0.x, 0.f); o0.y = fmaxf(o0.y, 0.f);
        o0.z = fmaxf(o0.z, 0.f); o0.w = fmaxf(o0.w, 0.f);
        o1.x = fmaxf(o1.x, 0.f); o1.y = fmaxf(o1.y, 0.f);
        o1.z = fmaxf(o1.z, 0.f); o1.w = fmaxf(o1.w, 0.f);
        if (gspan > 3) {
            float* dst = pooled + (size_t)batch[n] * H + c * BCW + l4 * 8;
            atomicAdd(dst + 0, o0.x); atomicAdd(dst + 1, o0.y);
            atomicAdd(dst + 2, o0.z); atomicAdd(dst + 3, o0.w);
            atomicAdd(dst + 4, o1.x); atomicAdd(dst + 5, o1.y);
            atomicAdd(dst + 6, o1.z); atomicAdd(dst + 7, o1.w);
        } else if (gspan == 0) {
            // single-graph block (common): shuffle-tree over slot bits (2..5)
#pragma unroll
            for (int m = 4; m <= 32; m <<= 1) {
                o0.x += __shfl_xor(o0.x, m); o0.y += __shfl_xor(o0.y, m);
                o0.z += __shfl_xor(o0.z, m); o0.w += __shfl_xor(o0.w, m);
                o1.x += __shfl_xor(o1.x, m); o1.y += __shfl_xor(o1.y, m);
                o1.z += __shfl_xor(o1.z, m); o1.w += __shfl_xor(o1.w, m);
            }
            if (slot == 0) {      // lane = l4 (0..3): wave-sum for feats l4*8..+7
                float* ps = &psum[wv][l4 * 8];
                ps[0] = o0.x; ps[1] = o0.y; ps[2] = o0.z; ps[3] = o0.w;
                ps[4] = o1.x; ps[5] = o1.y; ps[6] = o1.z; ps[7] = o1.w;
            }
            __syncthreads();
            if (tid < 32) {
                float v = psum[0][tid] + psum[1][tid] + psum[2][tid] + psum[3][tid];
                atomicAdd(&pooled[(size_t)g0 * H + c * BCW + tid], v);
            }
        } else {
            // graph-boundary block (~8%): LDS atomics (contention amortized)
            const int gi = batch[n] - g0;
            float* ps = &psum[gi][l4 * 8];
            atomicAdd(ps + 0, o0.x); atomicAdd(ps + 1, o0.y);
            atomicAdd(ps + 2, o0.z); atomicAdd(ps + 3, o0.w);
            atomicAdd(ps + 4, o1.x); atomicAdd(ps + 5, o1.y);
            atomicAdd(ps + 6, o1.z); atomicAdd(ps + 7, o1.w);
            __syncthreads();
            if (tid < 128) {
                int gi2 = tid >> 5, f = tid & 31;
                float v = psum[gi2][f];
                if (v != 0.f)
                    atomicAdd(&pooled[(size_t)(g0 + gi2) * H + c * BCW + f], v);
            }
        }
    }
}

// ---------------------------------------------------------------- helpers
__device__ __forceinline__ int lower_bound_dev(const int* __restrict__ b, int v) {
    int lo = 0, hi = NN;
    while (lo < hi) {
        int m = (lo + hi) >> 1;
        if (b[m] < v) lo = m + 1; else hi = m;
    }
    return lo;
}

// ---------------------------------------------------------------- LSTM (single step, h0=c0=0) + output head, fused
__global__ __launch_bounds__(256) void k_lstm(const float* __restrict__ pooled,
                                              const int* __restrict__ batch,
                                              const float* __restrict__ W_ih,
                                              const float* __restrict__ b_ih,
                                              const float* __restrict__ b_hh,
                                              const float* __restrict__ W_out,
                                              const float* __restrict__ b_out,
                                              float* __restrict__ out) {
    __shared__ __align__(16) float p[H];
    __shared__ __align__(16) float hn[LH];
    int g = blockIdx.x, t = threadIdx.x;
    if (t < H) {
        int s = lower_bound_dev(batch, g);
        int e = lower_bound_dev(batch, g + 1);
        p[t] = pooled[g * H + t] / fmaxf((float)(e - s), 1.f);
    }
    __syncthreads();

    // gate rows (torch order i,f,g,o): f unused (c0=0)
    float si = b_ih[t] + b_hh[t];
    float sg = b_ih[2 * LH + t] + b_hh[2 * LH + t];
    float so = b_ih[3 * LH + t] + b_hh[3 * LH + t];
    const float* wi = W_ih + (size_t)t * H;
    const float* wg = W_ih + (size_t)(2 * LH + t) * H;
    const float* wo = W_ih + (size_t)(3 * LH + t) * H;
    for (int k = 0; k < H; k += 4) {
        float4 pv = *reinterpret_cast<const float4*>(&p[k]);
        float4 a = *reinterpret_cast<const float4*>(wi + k);
        si += pv.x * a.x + pv.y * a.y + pv.z * a.z + pv.w * a.w;
        float4 b = *reinterpret_cast<const float4*>(wg + k);
        sg += pv.x * b.x + pv.y * b.y + pv.z * b.z + pv.w * b.w;
        float4 c = *reinterpret_cast<const float4*>(wo + k);
        so += pv.x * c.x + pv.y * c.y + pv.z * c.z + pv.w * c.w;
    }
    float ig = 1.f / (1.f + expf(-si));
    float cc = ig * tanhf(sg);
    float og = 1.f / (1.f + expf(-so));
    hn[t] = og * tanhf(cc);
    __syncthreads();

    if (t < OD) {
        float acc = b_out[t];
        const float* wr = W_out + (size_t)t * LH;
        for (int k = 0; k < LH; k += 4) {
            float4 hv = *reinterpret_cast<const float4*>(&hn[k]);
            float4 wv = *reinterpret_cast<const float4*>(wr + k);
            acc += hv.x * wv.x + hv.y * wv.y + hv.z * wv.z + hv.w * wv.w;
        }
        out[g * OD + t] = acc;
    }
}

// ----------------------------------------------------------------
extern "C" void kernel_launch(void* const* d_in, const int* in_sizes, int n_in,
                              void* d_out, int out_size, void* d_ws, size_t ws_size,
                              hipStream_t stream) {
    const float* x     = (const float*)d_in[0];
    const int*   ei    = (const int*)d_in[1];   // [2][NE]: rows then cols
    const int*   batch = (const int*)d_in[2];
    const float* Wg    = (const float*)d_in[3]; // [3][128][128]
    const float* bg    = (const float*)d_in[4]; // [3][128]
    const float* W_ih  = (const float*)d_in[5]; // [1024][128]
    const float* b_ih  = (const float*)d_in[7];
    const float* b_hh  = (const float*)d_in[8];
    const float* W_out = (const float*)d_in[9]; // [32][256]
    const float* b_out = (const float*)d_in[10];
    float* out = (float*)d_out;

    // workspace layout (~36 MB)
    unsigned short* tb   = (unsigned short*)d_ws;       // [4][NNP][32] bf16
    unsigned short* aggb = tb + (size_t)4 * NNP * BCW;  // [4][NNP][32] bf16
    int*   part      = (int*)(aggb + (size_t)4 * NNP * BCW); // NE ints (packed)
    float* dinv      = (float*)(part + NE);             // NN
    float* pooled    = dinv + NN;                       // NG*H
    int*   cnt       = (int*)(pooled + NG * H);         // NN
    int*   rp        = cnt + NN;                        // NN
    unsigned short* srcs = (unsigned short*)(rp + NN);  // NE+16 u16
    int*   bktCnt    = (int*)(srcs + NE + 16);          // NBKT
    int*   bktBase   = bktCnt + NBKT;                   // NBKT+1
    int*   bktCursor = bktBase + NBKT + 1;              // NBKT

    hipMemsetAsync(bktCnt, 0, NBKT * sizeof(int), stream);
    hipMemsetAsync(pooled, 0, NG * H * sizeof(float), stream);

    // CSR build (by destination) — bucketed counting sort (256-node buckets)
    k_bhist<<<512, 256, 0, stream>>>(ei + NE, bktCnt);
    k_bscan<<<1, 256, 0, stream>>>(bktCnt, bktBase, bktCursor, tb);
    k_part <<<NPARTB, 256, 0, stream>>>(ei, bktCursor, part);
    k_bfill<<<NBKT, 256, 0, stream>>>(bktBase, part, rp, cnt, dinv, srcs);

    const int gemmBlocks = (NN + 63) / 64;
    const int gathBlocks = ((NN + 63) / 64) * BCH;   // 782 * 4 = 3128

    // layer 0: x (fp32 row-major) -> tb -> aggb
    k_gemm<false, false><<<gemmBlocks, 256, 0, stream>>>(x, nullptr, Wg, dinv, tb);
    k_gather<0><<<gathBlocks, 256, 0, stream>>>(rp, cnt, srcs, dinv, bg, tb, aggb, batch, pooled);
    // layer 1: relu(aggb) -> tb -> aggb
    k_gemm<true, true><<<gemmBlocks, 256, 0, stream>>>(nullptr, aggb, Wg + H * H, dinv, tb);
    k_gather<0><<<gathBlocks, 256, 0, stream>>>(rp, cnt, srcs, dinv, bg + H, tb, aggb, batch, pooled);
    // layer 2: relu(aggb) -> tb -> pooled (pool fused)
    k_gemm<true, true><<<gemmBlocks, 256, 0, stream>>>(nullptr, aggb, Wg + 2 * H * H, dinv, tb);
    k_gather<1><<<gathBlocks, 256, 0, stream>>>(rp, cnt, srcs, dinv, bg + 2 * H, tb, nullptr, batch, pooled);

    k_lstm<<<NG, 256, 0, stream>>>(pooled, batch, W_ih, b_ih, b_hh, W_out, b_out, out);
}